// Round 1
// baseline (156.151 us; speedup 1.0000x reference)
//
#include <hip/hip_runtime.h>

// OrdLoss: N=2, C=16, D=32, H=128, W=128
// out = [ sum_{valid m} ( sum_{c<=t} log(clip(p)) + sum_{c>t} log(clip(1-p)) ) ] / ( -sum(valid) )

constexpr int    kC    = 16;
constexpr int    kDHW  = 32 * 128 * 128;        // 524288 voxels per sample
constexpr long   kM    = 2L * kDHW;             // 1048576 total voxels (N*D*H*W)
constexpr int    kBlock = 256;
constexpr int    kGrid  = (int)(kM / 4 / kBlock); // each thread handles 4 voxels -> 1024 blocks

// ws layout: ws[0] = double sum, ws[1] = u64 valid-count (bit-cast slot)
__global__ void zero_ws_kernel(unsigned long long* ws) {
    if (threadIdx.x == 0) {
        reinterpret_cast<double*>(ws)[0] = 0.0;
        ws[1] = 0ull;
    }
}

__global__ __launch_bounds__(kBlock)
void ordloss_kernel(const float* __restrict__ pred,
                    const int*   __restrict__ target,
                    const int*   __restrict__ mask,
                    double*      __restrict__ ws) {
    const int  tid  = blockIdx.x * blockDim.x + threadIdx.x;
    const long base = (long)tid * 4;                 // 4 consecutive w positions
    const int  n    = (int)(base / kDHW);
    const int  sp   = (int)(base - (long)n * kDHW);

    // mask is (N,1,D,H,W) -> flat index == base
    const int4 mk = *reinterpret_cast<const int4*>(mask + base);
    // target replicated along C -> read channel 0 only (saves 60 MiB of traffic)
    const int4 tg = *reinterpret_cast<const int4*>(target + (size_t)n * kC * kDHW + sp);

    const float* pbase = pred + (size_t)n * kC * kDHW + sp;

    float acc0 = 0.f, acc1 = 0.f, acc2 = 0.f, acc3 = 0.f;
    const int t0 = tg.x, t1 = tg.y, t2 = tg.z, t3 = tg.w;

    #pragma unroll
    for (int c = 0; c < kC; ++c) {
        const float4 p = *reinterpret_cast<const float4*>(pbase + (size_t)c * kDHW);
        float x0 = (c <= t0) ? p.x : 1.0f - p.x;
        float x1 = (c <= t1) ? p.y : 1.0f - p.y;
        float x2 = (c <= t2) ? p.z : 1.0f - p.z;
        float x3 = (c <= t3) ? p.w : 1.0f - p.w;
        acc0 += __logf(fmaxf(x0, 1e-8f));   // p in [0,1): only the lower clip can bind
        acc1 += __logf(fmaxf(x1, 1e-8f));
        acc2 += __logf(fmaxf(x2, 1e-8f));
        acc3 += __logf(fmaxf(x3, 1e-8f));
    }

    float lsum = (mk.x > 0 ? acc0 : 0.f) + (mk.y > 0 ? acc1 : 0.f)
               + (mk.z > 0 ? acc2 : 0.f) + (mk.w > 0 ? acc3 : 0.f);
    int   lcnt = (mk.x > 0) + (mk.y > 0) + (mk.z > 0) + (mk.w > 0);

    // wave64 butterfly reduce
    #pragma unroll
    for (int off = 32; off > 0; off >>= 1) {
        lsum += __shfl_down(lsum, off);
        lcnt += __shfl_down(lcnt, off);
    }

    __shared__ float swave[kBlock / 64];
    __shared__ int   cwave[kBlock / 64];
    const int lane = threadIdx.x & 63;
    const int wid  = threadIdx.x >> 6;
    if (lane == 0) { swave[wid] = lsum; cwave[wid] = lcnt; }
    __syncthreads();
    if (threadIdx.x == 0) {
        float bs = swave[0] + swave[1] + swave[2] + swave[3];
        int   bc = cwave[0] + cwave[1] + cwave[2] + cwave[3];
        atomicAdd(ws, (double)bs);                                      // 1 per block
        atomicAdd(reinterpret_cast<unsigned long long*>(ws) + 1,
                  (unsigned long long)bc);
    }
}

__global__ void finalize_kernel(const double* __restrict__ ws,
                                float* __restrict__ out) {
    if (threadIdx.x == 0) {
        const double s   = ws[0];
        const double cnt = (double)reinterpret_cast<const unsigned long long*>(ws)[1];
        out[0] = (float)(s / (-cnt));
    }
}

extern "C" void kernel_launch(void* const* d_in, const int* in_sizes, int n_in,
                              void* d_out, int out_size, void* d_ws, size_t ws_size,
                              hipStream_t stream) {
    const float* pred   = (const float*)d_in[0];
    const int*   target = (const int*)d_in[1];
    const int*   mask   = (const int*)d_in[2];
    double*      ws     = (double*)d_ws;     // re-poisoned 0xAA before every launch
    float*       out    = (float*)d_out;

    zero_ws_kernel<<<1, 64, 0, stream>>>((unsigned long long*)ws);
    ordloss_kernel<<<kGrid, kBlock, 0, stream>>>(pred, target, mask, ws);
    finalize_kernel<<<1, 64, 0, stream>>>(ws, out);
}

// Round 2
// 137.212 us; speedup vs baseline: 1.1380x; 1.1380x over previous
//
#include <hip/hip_runtime.h>

// OrdLoss: N=2, C=16, D=32, H=128, W=128
// out = [ sum_{valid m} ( sum_{c<=t} log(clip(p)) + sum_{c>t} log(clip(1-p)) ) ] / ( -sum(valid) )
//
// R1 design: latency-bound fix. Each thread owns 4 consecutive voxels and
// prefetches ALL 16 channel float4 loads into registers before computing
// (18 outstanding loads/thread). No atomics: per-block partials -> ws,
// second kernel reduces 1024 partials.

constexpr int  kC     = 16;
constexpr int  kDHW   = 32 * 128 * 128;   // 524288 = 2^19
constexpr long kM     = 2L * kDHW;        // 1048576 voxels
constexpr int  kBlock = 256;
constexpr int  kVox   = 4;                // voxels per thread (one float4 per channel)
constexpr int  kGrid  = (int)(kM / kVox / kBlock);   // 1024 blocks

__global__ __launch_bounds__(kBlock)
void ordloss_main(const float* __restrict__ pred,
                  const int*   __restrict__ target,
                  const int*   __restrict__ mask,
                  float*       __restrict__ bsum,
                  int*         __restrict__ bcnt) {
    const int  tid  = blockIdx.x * kBlock + threadIdx.x;
    const long base = (long)tid * kVox;
    const int  n    = (int)(base >> 19);             // base / kDHW
    const int  sp   = (int)(base & (kDHW - 1));

    // ---- issue ALL loads up front (compiler keeps them in flight) ----
    const float* pb = pred + ((size_t)n << 23) + sp; // n*16*kDHW
    float4 p[kC];
    #pragma unroll
    for (int c = 0; c < kC; ++c)
        p[c] = *reinterpret_cast<const float4*>(pb + ((size_t)c << 19));
    const int4 mk = *reinterpret_cast<const int4*>(mask + base);
    const int4 tg = *reinterpret_cast<const int4*>(target + ((size_t)n << 23) + sp);

    // ---- compute: 64 logs, 4 independent accumulator chains ----
    float acc0 = 0.f, acc1 = 0.f, acc2 = 0.f, acc3 = 0.f;
    #pragma unroll
    for (int c = 0; c < kC; ++c) {
        float x0 = (c <= tg.x) ? p[c].x : 1.0f - p[c].x;
        float x1 = (c <= tg.y) ? p[c].y : 1.0f - p[c].y;
        float x2 = (c <= tg.z) ? p[c].z : 1.0f - p[c].z;
        float x3 = (c <= tg.w) ? p[c].w : 1.0f - p[c].w;
        acc0 += __logf(fmaxf(x0, 1e-8f));   // p in [0,1): only the lower clip binds
        acc1 += __logf(fmaxf(x1, 1e-8f));
        acc2 += __logf(fmaxf(x2, 1e-8f));
        acc3 += __logf(fmaxf(x3, 1e-8f));
    }

    float lsum = (mk.x > 0 ? acc0 : 0.f) + (mk.y > 0 ? acc1 : 0.f)
               + (mk.z > 0 ? acc2 : 0.f) + (mk.w > 0 ? acc3 : 0.f);
    int   lcnt = (mk.x > 0) + (mk.y > 0) + (mk.z > 0) + (mk.w > 0);

    // ---- wave64 reduce, then LDS, then one plain store per block ----
    #pragma unroll
    for (int off = 32; off > 0; off >>= 1) {
        lsum += __shfl_down(lsum, off);
        lcnt += __shfl_down(lcnt, off);
    }
    __shared__ float swave[kBlock / 64];
    __shared__ int   cwave[kBlock / 64];
    const int lane = threadIdx.x & 63;
    const int wid  = threadIdx.x >> 6;
    if (lane == 0) { swave[wid] = lsum; cwave[wid] = lcnt; }
    __syncthreads();
    if (threadIdx.x == 0) {
        bsum[blockIdx.x] = swave[0] + swave[1] + swave[2] + swave[3];
        bcnt[blockIdx.x] = cwave[0] + cwave[1] + cwave[2] + cwave[3];
    }
}

// 1 block, 256 threads: reduce 1024 partials, write the scalar.
__global__ __launch_bounds__(kBlock)
void ordloss_reduce(const float* __restrict__ bsum,
                    const int*   __restrict__ bcnt,
                    float*       __restrict__ out) {
    const float4 s4 = *reinterpret_cast<const float4*>(bsum + threadIdx.x * 4);
    const int4   c4 = *reinterpret_cast<const int4*>(bcnt + threadIdx.x * 4);
    double s = (double)s4.x + s4.y + s4.z + s4.w;
    long   c = (long)c4.x + c4.y + c4.z + c4.w;
    #pragma unroll
    for (int off = 32; off > 0; off >>= 1) {
        s += __shfl_down(s, off);
        c += __shfl_down(c, off);
    }
    __shared__ double sw[kBlock / 64];
    __shared__ long   cw[kBlock / 64];
    const int lane = threadIdx.x & 63;
    const int wid  = threadIdx.x >> 6;
    if (lane == 0) { sw[wid] = s; cw[wid] = c; }
    __syncthreads();
    if (threadIdx.x == 0) {
        double S = sw[0] + sw[1] + sw[2] + sw[3];
        long   C = cw[0] + cw[1] + cw[2] + cw[3];
        out[0] = (float)(S / (double)(-C));
    }
}

extern "C" void kernel_launch(void* const* d_in, const int* in_sizes, int n_in,
                              void* d_out, int out_size, void* d_ws, size_t ws_size,
                              hipStream_t stream) {
    const float* pred   = (const float*)d_in[0];
    const int*   target = (const int*)d_in[1];
    const int*   mask   = (const int*)d_in[2];
    float*       bsum   = (float*)d_ws;               // 1024 floats
    int*         bcnt   = (int*)((char*)d_ws + kGrid * sizeof(float)); // 1024 ints
    float*       out    = (float*)d_out;

    ordloss_main<<<kGrid, kBlock, 0, stream>>>(pred, target, mask, bsum, bcnt);
    ordloss_reduce<<<1, kBlock, 0, stream>>>(bsum, bcnt, out);
}